// Round 4
// baseline (530.157 us; speedup 1.0000x reference)
//
#include <hip/hip_runtime.h>
#include <cstddef>
#include <cstdint>

#define B_ 4
#define N_ 1024
#define C_ 768
#define H_ 12
#define D_ 64

typedef __attribute__((ext_vector_type(8))) short bf16x8;
typedef __attribute__((ext_vector_type(4))) short s16x4;
typedef __attribute__((ext_vector_type(4))) float f32x4;

#define MFMA16(a_, b_, c_) __builtin_amdgcn_mfma_f32_16x16x32_bf16((a_), (b_), (c_), 0, 0, 0)
#define GLLDS16(gp_, lp_) __builtin_amdgcn_global_load_lds( \
    (const __attribute__((address_space(1))) unsigned int*)(gp_), \
    (__attribute__((address_space(3))) unsigned int*)(lp_), 16, 0, 0)

__device__ __forceinline__ unsigned short f2bf(float f) {
  unsigned int u = __float_as_uint(f);
  u += 0x7fffu + ((u >> 16) & 1u);
  return (unsigned short)(u >> 16);
}
__device__ __forceinline__ float bf2f(unsigned short b) {
  return __uint_as_float(((unsigned int)b) << 16);
}

// ---------------- split x (elementwise, 8 elems/thread) ----------------
__global__ __launch_bounds__(256) void k_split_x(const float* __restrict__ x,
                                                 short* __restrict__ xhi,
                                                 short* __restrict__ xlo) {
  const size_t i = ((size_t)blockIdx.x * 256 + threadIdx.x) * 8;
  float4 a = *reinterpret_cast<const float4*>(&x[i]);
  float4 b = *reinterpret_cast<const float4*>(&x[i + 4]);
  float v[8] = {a.x, a.y, a.z, a.w, b.x, b.y, b.z, b.w};
  bf16x8 hi, lo;
#pragma unroll
  for (int j = 0; j < 8; ++j) {
    unsigned short h = f2bf(v[j]);
    hi[j] = (short)h;
    lo[j] = (short)f2bf(v[j] - bf2f(h));
  }
  *reinterpret_cast<bf16x8*>(&xhi[i]) = hi;
  *reinterpret_cast<bf16x8*>(&xlo[i]) = lo;
}

// ---------------- split + transpose weights: W[Kd][Nn] -> T[Nn][Kd] hi/lo ----------------
__global__ __launch_bounds__(256) void k_split_T(const float* __restrict__ W,
                                                 short* __restrict__ Thi,
                                                 short* __restrict__ Tlo,
                                                 int Kd, int Nn) {
  __shared__ float tile[32][33];
  const int k0 = blockIdx.y * 32, n0 = blockIdx.x * 32;
  const int t = threadIdx.x;
  const int r = t >> 3, cq = (t & 7) * 4;
  float4 v = *reinterpret_cast<const float4*>(&W[(size_t)(k0 + r) * Nn + n0 + cq]);
  tile[r][cq + 0] = v.x; tile[r][cq + 1] = v.y;
  tile[r][cq + 2] = v.z; tile[r][cq + 3] = v.w;
  __syncthreads();
  const int nrow = t >> 3, kq = (t & 7) * 4;
  s16x4 hi, lo;
#pragma unroll
  for (int i = 0; i < 4; ++i) {
    float f = tile[kq + i][nrow];
    unsigned short h = f2bf(f);
    hi[i] = (short)h;
    lo[i] = (short)f2bf(f - bf2f(h));
  }
  *reinterpret_cast<s16x4*>(&Thi[(size_t)(n0 + nrow) * Kd + k0 + kq]) = hi;
  *reinterpret_cast<s16x4*>(&Tlo[(size_t)(n0 + nrow) * Kd + k0 + kq]) = lo;
}

// ---------------- fold scale/riem into W_conv ----------------
__global__ __launch_bounds__(256) void k_fold(const float* __restrict__ Wc,
                                              const float* __restrict__ scale_p,
                                              const float* __restrict__ riem_p,
                                              float* __restrict__ Wfold) {
  const int t = threadIdx.x;
  const float scale = scale_p[0], riem = riem_p[0];
  for (int i = t; i < 288; i += 256)
    Wfold[i] = Wc[i] * (((i % 24) < 12) ? scale : riem);
}

// ---------------- generic split-bf16 MFMA GEMM ----------------
// C[M][Nn] = A[M][Kd] * B^T (B stored [Nn][Kd]) + bias[n];  BM=128 BN=64 BK=32
__global__ __launch_bounds__(256) void k_gemm(const short* __restrict__ Ahi,
                                              const short* __restrict__ Alo,
                                              const short* __restrict__ Bhi,
                                              const short* __restrict__ Blo,
                                              const float* __restrict__ bias,
                                              float* __restrict__ Cout,
                                              int M, int Nn, int Kd) {
  __shared__ __align__(16) short sA[2][128 * 32];
  __shared__ __align__(16) short sB[2][64 * 32];
  const int tid = threadIdx.x;
  const int wv = tid >> 6, l = tid & 63;
  const int lr = l & 15, lg = l >> 4;
  const int row0 = blockIdx.y * 128;
  const int col0 = blockIdx.x * 64;
  const int wr = (wv >> 1) * 64;
  const int wc = (wv & 1) * 32;
  const int ar = tid >> 2, ac = tid & 3;
  f32x4 acc[4][2];
#pragma unroll
  for (int i = 0; i < 4; ++i)
#pragma unroll
    for (int j = 0; j < 2; ++j) acc[i][j] = (f32x4){0.f, 0.f, 0.f, 0.f};

  for (int k0 = 0; k0 < Kd; k0 += 32) {
#pragma unroll
    for (int j = 0; j < 2; ++j) {
      const int row = j * 64 + ar;
      const int cc = ac ^ ((row >> 1) & 3);
      const size_t so = (size_t)(row0 + row) * Kd + k0 + cc * 8;
      GLLDS16(Ahi + so, &sA[0][(j * 256 + (wv << 6)) * 8]);
      GLLDS16(Alo + so, &sA[1][(j * 256 + (wv << 6)) * 8]);
    }
    {
      const int row = ar;
      const int cc = ac ^ ((row >> 1) & 3);
      const size_t so = (size_t)(col0 + row) * Kd + k0 + cc * 8;
      GLLDS16(Bhi + so, &sB[0][(wv << 6) * 8]);
      GLLDS16(Blo + so, &sB[1][(wv << 6) * 8]);
    }
    __syncthreads();
    bf16x8 afh[4], afl[4], bfh[2], bfl[2];
#pragma unroll
    for (int ti = 0; ti < 4; ++ti) {
      const int row = wr + ti * 16 + lr;
      const int pc = lg ^ ((row >> 1) & 3);
      afh[ti] = *reinterpret_cast<const bf16x8*>(&sA[0][row * 32 + pc * 8]);
      afl[ti] = *reinterpret_cast<const bf16x8*>(&sA[1][row * 32 + pc * 8]);
    }
#pragma unroll
    for (int tj = 0; tj < 2; ++tj) {
      const int row = wc + tj * 16 + lr;
      const int pc = lg ^ ((row >> 1) & 3);
      bfh[tj] = *reinterpret_cast<const bf16x8*>(&sB[0][row * 32 + pc * 8]);
      bfl[tj] = *reinterpret_cast<const bf16x8*>(&sB[1][row * 32 + pc * 8]);
    }
#pragma unroll
    for (int ti = 0; ti < 4; ++ti)
#pragma unroll
      for (int tj = 0; tj < 2; ++tj) {
        acc[ti][tj] = MFMA16(afh[ti], bfh[tj], acc[ti][tj]);
        acc[ti][tj] = MFMA16(afl[ti], bfh[tj], acc[ti][tj]);
        acc[ti][tj] = MFMA16(afh[ti], bfl[tj], acc[ti][tj]);
      }
    __syncthreads();
  }
#pragma unroll
  for (int ti = 0; ti < 4; ++ti)
#pragma unroll
    for (int tj = 0; tj < 2; ++tj) {
      const int col = col0 + wc + tj * 16 + lr;
      const float bb = bias[col];
#pragma unroll
      for (int r = 0; r < 4; ++r) {
        const int row = row0 + wr + ti * 16 + lg * 4 + r;
        Cout[(size_t)row * Nn + col] = acc[ti][tj][r] + bb;
      }
    }
}

// ---------------- qkv post: split Q/K, transpose+split V ----------------
__global__ __launch_bounds__(256) void k_qkv_post(const float* __restrict__ qkvf,
                                                  short* __restrict__ Qhi, short* __restrict__ Qlo,
                                                  short* __restrict__ Khi, short* __restrict__ Klo,
                                                  short* __restrict__ Vthi, short* __restrict__ Vtlo) {
  __shared__ unsigned short lvh[64][33];
  __shared__ unsigned short lvl[64][33];
  const int b = blockIdx.z, h = blockIdx.y, n0 = blockIdx.x * 32;
  const int t = threadIdx.x;
  const int row = t >> 3, d0 = (t & 7) * 8;
  const int n = n0 + row;
  const float* base = qkvf + ((size_t)(b * 1024 + n)) * 2304 + h * 64 + d0;
  const size_t qko = ((size_t)(b * H_ + h) * N_ + n) * D_ + d0;

#pragma unroll
  for (int part = 0; part < 2; ++part) {  // 0: q, 1: k
    float4 a = *reinterpret_cast<const float4*>(base + part * 768);
    float4 c = *reinterpret_cast<const float4*>(base + part * 768 + 4);
    float v[8] = {a.x, a.y, a.z, a.w, c.x, c.y, c.z, c.w};
    bf16x8 hi, lo;
#pragma unroll
    for (int j = 0; j < 8; ++j) {
      unsigned short hh = f2bf(v[j]);
      hi[j] = (short)hh;
      lo[j] = (short)f2bf(v[j] - bf2f(hh));
    }
    *reinterpret_cast<bf16x8*>((part ? Khi : Qhi) + qko) = hi;
    *reinterpret_cast<bf16x8*>((part ? Klo : Qlo) + qko) = lo;
  }
  {  // v -> transposed split
    float4 a = *reinterpret_cast<const float4*>(base + 1536);
    float4 c = *reinterpret_cast<const float4*>(base + 1536 + 4);
    float v[8] = {a.x, a.y, a.z, a.w, c.x, c.y, c.z, c.w};
#pragma unroll
    for (int j = 0; j < 8; ++j) {
      unsigned short hh = f2bf(v[j]);
      lvh[d0 + j][row] = hh;
      lvl[d0 + j][row] = f2bf(v[j] - bf2f(hh));
    }
  }
  __syncthreads();
  const int d = t >> 2, c = t & 3;
  bf16x8 vh, vl;
#pragma unroll
  for (int i = 0; i < 8; ++i) {
    vh[i] = (short)lvh[d][c * 8 + i];
    vl[i] = (short)lvl[d][c * 8 + i];
  }
  const size_t vo = ((size_t)(b * H_ + h) * D_ + d) * N_ + n0 + c * 8;
  *reinterpret_cast<bf16x8*>(Vthi + vo) = vh;
  *reinterpret_cast<bf16x8*>(Vtlo + vo) = vl;
}

// ---------------- center K: KC = K - rowmean(K), split bf16 ----------------
__global__ __launch_bounds__(256) void k_center(const short* __restrict__ Khi,
                                                const short* __restrict__ Klo,
                                                short* __restrict__ KChi,
                                                short* __restrict__ KClo) {
  const size_t row = (size_t)blockIdx.x * 32 + (threadIdx.x >> 3);
  const int d0 = (threadIdx.x & 7) * 8;
  const size_t off = row * D_ + d0;
  bf16x8 hi = *reinterpret_cast<const bf16x8*>(Khi + off);
  bf16x8 lo = *reinterpret_cast<const bf16x8*>(Klo + off);
  float v[8];
  float s = 0.f;
#pragma unroll
  for (int j = 0; j < 8; ++j) {
    v[j] = bf2f((unsigned short)hi[j]) + bf2f((unsigned short)lo[j]);
    s += v[j];
  }
#pragma unroll
  for (int o = 1; o < 8; o <<= 1) s += __shfl_xor(s, o);
  const float km = s * (1.0f / 64.0f);
  bf16x8 ch, cl;
#pragma unroll
  for (int j = 0; j < 8; ++j) {
    const float f = v[j] - km;
    unsigned short hh = f2bf(f);
    ch[j] = (short)hh;
    cl[j] = (short)f2bf(f - bf2f(hh));
  }
  *reinterpret_cast<bf16x8*>(KChi + off) = ch;
  *reinterpret_cast<bf16x8*>(KClo + off) = cl;
}

// ---------------- scores + channel mix -> logits (+ partial softmax stats) ----------------
// s = q.k, u = q.kc (kc centered => u = qc.kc); logit[o] = sum_h We'[o,h]*s + Wr'[o,h]*u^2
__global__ __launch_bounds__(256) void k_scores(
    const short* __restrict__ Qhi, const short* __restrict__ Qlo,
    const short* __restrict__ Khi, const short* __restrict__ Klo,
    const short* __restrict__ KChi, const short* __restrict__ KClo,
    const float* __restrict__ Wfold, float* __restrict__ logits,
    float2* __restrict__ stats) {
  __shared__ float2 sbuf[4][12][16];
  const int tid = threadIdx.x;
  const int b = blockIdx.z;
  const int n0 = blockIdx.y * 32, m0 = blockIdx.x * 32;
  const int w = tid >> 6, l = tid & 63;
  const int nb = n0 + (w >> 1) * 16;
  const int mb = m0 + (w & 1) * 16;
  const int lr = l & 15, lg = l >> 4;
  f32x4 acc[12];
#pragma unroll
  for (int o = 0; o < 12; ++o) acc[o] = (f32x4){0.f, 0.f, 0.f, 0.f};

  const size_t bq0 = (((size_t)b * H_) * N_ + nb + lr) * D_ + lg * 8;
  const size_t bk0 = (((size_t)b * H_) * N_ + mb + lr) * D_ + lg * 8;
  const size_t hstep = (size_t)N_ * D_;

  bf16x8 qh0 = *reinterpret_cast<const bf16x8*>(Qhi + bq0);
  bf16x8 qh1 = *reinterpret_cast<const bf16x8*>(Qhi + bq0 + 32);
  bf16x8 ql0 = *reinterpret_cast<const bf16x8*>(Qlo + bq0);
  bf16x8 ql1 = *reinterpret_cast<const bf16x8*>(Qlo + bq0 + 32);
  bf16x8 kh0 = *reinterpret_cast<const bf16x8*>(Khi + bk0);
  bf16x8 kh1 = *reinterpret_cast<const bf16x8*>(Khi + bk0 + 32);
  bf16x8 kl0 = *reinterpret_cast<const bf16x8*>(Klo + bk0);
  bf16x8 kl1 = *reinterpret_cast<const bf16x8*>(Klo + bk0 + 32);
  bf16x8 ch0 = *reinterpret_cast<const bf16x8*>(KChi + bk0);
  bf16x8 ch1 = *reinterpret_cast<const bf16x8*>(KChi + bk0 + 32);
  bf16x8 cl0 = *reinterpret_cast<const bf16x8*>(KClo + bk0);
  bf16x8 cl1 = *reinterpret_cast<const bf16x8*>(KClo + bk0 + 32);

  for (int h = 0; h < H_; ++h) {
    bf16x8 nqh0, nqh1, nql0, nql1, nkh0, nkh1, nkl0, nkl1, nch0, nch1, ncl0, ncl1;
    if (h < 11) {
      const size_t bq = bq0 + (h + 1) * hstep;
      const size_t bk = bk0 + (h + 1) * hstep;
      nqh0 = *reinterpret_cast<const bf16x8*>(Qhi + bq);
      nqh1 = *reinterpret_cast<const bf16x8*>(Qhi + bq + 32);
      nql0 = *reinterpret_cast<const bf16x8*>(Qlo + bq);
      nql1 = *reinterpret_cast<const bf16x8*>(Qlo + bq + 32);
      nkh0 = *reinterpret_cast<const bf16x8*>(Khi + bk);
      nkh1 = *reinterpret_cast<const bf16x8*>(Khi + bk + 32);
      nkl0 = *reinterpret_cast<const bf16x8*>(Klo + bk);
      nkl1 = *reinterpret_cast<const bf16x8*>(Klo + bk + 32);
      nch0 = *reinterpret_cast<const bf16x8*>(KChi + bk);
      nch1 = *reinterpret_cast<const bf16x8*>(KChi + bk + 32);
      ncl0 = *reinterpret_cast<const bf16x8*>(KClo + bk);
      ncl1 = *reinterpret_cast<const bf16x8*>(KClo + bk + 32);
    }
    f32x4 s = {0.f, 0.f, 0.f, 0.f};
    f32x4 u = {0.f, 0.f, 0.f, 0.f};
    // two independent MFMA chains, interleaved
    s = MFMA16(qh0, kh0, s);  u = MFMA16(qh0, ch0, u);
    s = MFMA16(qh1, kh1, s);  u = MFMA16(qh1, ch1, u);
    s = MFMA16(qh0, kl0, s);  u = MFMA16(qh0, cl0, u);
    s = MFMA16(qh1, kl1, s);  u = MFMA16(qh1, cl1, u);
    s = MFMA16(ql0, kh0, s);  u = MFMA16(ql0, ch0, u);
    s = MFMA16(ql1, kh1, s);  u = MFMA16(ql1, ch1, u);

    float u2[4];
#pragma unroll
    for (int r = 0; r < 4; ++r) u2[r] = u[r] * u[r];
#pragma unroll
    for (int o = 0; o < 12; ++o) {
      const float we = Wfold[o * 24 + h];
      const float wr = Wfold[o * 24 + 12 + h];
#pragma unroll
      for (int r = 0; r < 4; ++r)
        acc[o][r] = fmaf(we, s[r], fmaf(wr, u2[r], acc[o][r]));
    }
    qh0 = nqh0; qh1 = nqh1; ql0 = nql0; ql1 = nql1;
    kh0 = nkh0; kh1 = nkh1; kl0 = nkl0; kl1 = nkl1;
    ch0 = nch0; ch1 = nch1; cl0 = ncl0; cl1 = ncl1;
  }
  // write logits
#pragma unroll
  for (int o = 0; o < 12; ++o) {
    float* dst = &logits[(((size_t)b * H_ + o) * N_ + nb) * N_ + mb + lr];
#pragma unroll
    for (int r = 0; r < 4; ++r)
      dst[(size_t)(lg * 4 + r) * N_] = acc[o][r];
  }
  // partial stats over this wave's 16 m, merge wave pairs (32 m)
#pragma unroll
  for (int o = 0; o < 12; ++o) {
    float mx4[4], ss4[4];
#pragma unroll
    for (int r = 0; r < 4; ++r) {
      float mx = acc[o][r];
      mx = fmaxf(mx, __shfl_xor(mx, 1));
      mx = fmaxf(mx, __shfl_xor(mx, 2));
      mx = fmaxf(mx, __shfl_xor(mx, 4));
      mx = fmaxf(mx, __shfl_xor(mx, 8));
      float e = __expf(acc[o][r] - mx);
      e += __shfl_xor(e, 1);
      e += __shfl_xor(e, 2);
      e += __shfl_xor(e, 4);
      e += __shfl_xor(e, 8);
      mx4[r] = mx; ss4[r] = e;
    }
    if (lr < 4) sbuf[w][o][lg * 4 + lr] = make_float2(mx4[lr], ss4[lr]);
  }
  __syncthreads();
  if ((w & 1) == 0) {
    for (int i = l; i < 192; i += 64) {
      const int o = i >> 4, row = i & 15;
      const float2 p0 = sbuf[w][o][row];
      const float2 p1 = sbuf[w + 1][o][row];
      const float M = fmaxf(p0.x, p1.x);
      const float S = p0.y * __expf(p0.x - M) + p1.y * __expf(p1.x - M);
      const int n = n0 + (w >> 1) * 16 + row;
      stats[(((size_t)b * 12 + o) * 32 + blockIdx.x) * 1024 + n] = make_float2(M, S);
    }
  }
}

// ---------------- merge partial stats -> per-row (M, 1/S) ----------------
__global__ __launch_bounds__(256) void k_merge(const float2* __restrict__ stats,
                                               float2* __restrict__ merged) {
  const int bo = blockIdx.y;
  const int n = blockIdx.x * 256 + threadIdx.x;
  float M = -3.0e38f, S = 0.f;
  for (int seg = 0; seg < 32; ++seg) {
    const float2 p = stats[((size_t)bo * 32 + seg) * 1024 + n];
    if (p.x > M) {
      S = S * __expf(M - p.x) + p.y;
      M = p.x;
    } else {
      S += p.y * __expf(p.x - M);
    }
  }
  merged[(size_t)bo * 1024 + n] = make_float2(M, 1.0f / S);
}

// ---------------- fused softmax + attn-write + PV MFMA + split epilogue ----------------
__global__ __launch_bounds__(256) void k_pvsm(float* __restrict__ attn,
                                              const float2* __restrict__ merged,
                                              const short* __restrict__ Vthi,
                                              const short* __restrict__ Vtlo,
                                              short* __restrict__ ohi,
                                              short* __restrict__ olo) {
  __shared__ __align__(16) short sPhi[32 * 32];
  __shared__ __align__(16) short sPlo[32 * 32];
  __shared__ __align__(16) short sVhi[64 * 32];
  __shared__ __align__(16) short sVlo[64 * 32];
  __shared__ float sM[32], sIS[32];
  const int b = blockIdx.z, o = blockIdx.y;
  const int n0 = blockIdx.x * 32;
  const int bo = b * H_ + o;
  const int t = threadIdx.x;
  const int wv = t >> 6, l = t & 63;
  const int lr = l & 15, lg = l >> 4;
  const int nsub = (wv & 1) * 16, dsub = (wv >> 1) * 32;

  if (t < 32) {
    const float2 ms = merged[(size_t)bo * 1024 + n0 + t];
    sM[t] = ms.x;
    sIS[t] = ms.y;
  }
  __syncthreads();

  const int prow = t >> 3, pc4 = (t & 7) * 4;
  float* lrow = attn + ((size_t)bo * N_ + n0 + prow) * N_ + pc4;
  const int vd = t >> 2, vc = t & 3;
  const int vcc = vc ^ ((vd >> 1) & 3);
  const size_t vsrc0 = ((size_t)bo * D_ + vd) * N_ + vcc * 8;
  const int pchunk = (pc4 >> 3) ^ ((prow >> 1) & 3);
  const int pofs = prow * 32 + pchunk * 8 + (t & 1) * 4;

  f32x4 acc[2];
  acc[0] = (f32x4){0.f, 0.f, 0.f, 0.f};
  acc[1] = (f32x4){0.f, 0.f, 0.f, 0.f};

  for (int ms = 0; ms < 32; ++ms) {
    const int m0 = ms * 32;
    GLLDS16(Vthi + vsrc0 + m0, &sVhi[(wv << 6) * 8]);
    GLLDS16(Vtlo + vsrc0 + m0, &sVlo[(wv << 6) * 8]);
    float4 lv = *reinterpret_cast<const float4*>(&lrow[m0]);
    const float Mr = sM[prow], iS = sIS[prow];
    float4 p;
    p.x = __expf(lv.x - Mr) * iS;
    p.y = __expf(lv.y - Mr) * iS;
    p.z = __expf(lv.z - Mr) * iS;
    p.w = __expf(lv.w - Mr) * iS;
    *reinterpret_cast<float4*>(&lrow[m0]) = p;
    const float pv[4] = {p.x, p.y, p.z, p.w};
    s16x4 phi, plo;
#pragma unroll
    for (int j = 0; j < 4; ++j) {
      unsigned short hh = f2bf(pv[j]);
      phi[j] = (short)hh;
      plo[j] = (short)f2bf(pv[j] - bf2f(hh));
    }
    *reinterpret_cast<s16x4*>(&sPhi[pofs]) = phi;
    *reinterpret_cast<s16x4*>(&sPlo[pofs]) = plo;
    __syncthreads();
    const int arow = nsub + lr;
    const int apc = lg ^ ((arow >> 1) & 3);
    const bf16x8 pa = *reinterpret_cast<const bf16x8*>(&sPhi[arow * 32 + apc * 8]);
    const bf16x8 pb = *reinterpret_cast<const bf16x8*>(&sPlo[arow * 32 + apc * 8]);
#pragma unroll
    for (int dt = 0; dt < 2; ++dt) {
      const int drow = dsub + dt * 16 + lr;
      const int dpc = lg ^ ((drow >> 1) & 3);
      const bf16x8 vh = *reinterpret_cast<const bf16x8*>(&sVhi[drow * 32 + dpc * 8]);
      const bf16x8 vl = *reinterpret_cast<const bf16x8*>(&sVlo[drow * 32 + dpc * 8]);
      acc[dt] = MFMA16(pa, vh, acc[dt]);
      acc[dt] = MFMA16(pb, vh, acc[dt]);
      acc[dt] = MFMA16(pa, vl, acc[dt]);
    }
    __syncthreads();
  }
#pragma unroll
  for (int dt = 0; dt < 2; ++dt) {
    const int d = dsub + dt * 16 + lr;
#pragma unroll
    for (int r = 0; r < 4; ++r) {
      const int n = n0 + nsub + lg * 4 + r;
      const float val = acc[dt][r];
      const unsigned short hh = f2bf(val);
      const size_t oo = (size_t)(b * 1024 + n) * 768 + o * 64 + d;
      ohi[oo] = (short)hh;
      olo[oo] = (short)f2bf(val - bf2f(hh));
    }
  }
}

extern "C" void kernel_launch(void* const* d_in, const int* in_sizes, int n_in,
                              void* d_out, int out_size, void* d_ws, size_t ws_size,
                              hipStream_t stream) {
  (void)in_sizes; (void)n_in; (void)out_size; (void)ws_size;
  const float* x      = (const float*)d_in[0];
  const float* W_qkv  = (const float*)d_in[1];
  const float* b_qkv  = (const float*)d_in[2];
  const float* scale  = (const float*)d_in[3];
  const float* riem   = (const float*)d_in[4];
  const float* W_conv = (const float*)d_in[5];
  // d_in[6] = b_conv: constant along softmax axis -> softmax-invariant, skipped
  const float* W_proj = (const float*)d_in[7];
  const float* b_proj = (const float*)d_in[8];

  float* out_final = (float*)d_out;                     // [B,N,C]
  float* attn_out  = out_final + (size_t)B_ * N_ * C_;  // [B,H,N,N] logits -> attn in-place

  char* w = (char*)d_ws;
  short* xhi  = (short*)w;                       // 6291456 B
  short* xlo  = xhi + 3145728;                   // 6291456 B
  short* Wthi = (short*)(w + 12582912);          // 3538944 B
  short* Wtlo = Wthi + 1769472;                  // 3538944 B
  short* Wpthi = (short*)(w + 19660800);         // 1179648 B
  short* Wptlo = Wpthi + 589824;                 // 1179648 B
  float* qkvf = (float*)(w + 22020096);          // 37748736 B
  short* Qhi  = (short*)(w + 59768832);
  short* Qlo  = Qhi + 3145728;
  short* Khi  = Qlo + 3145728;
  short* Klo  = Khi + 3145728;                   // ws end: 84934656 B
  // aliases (lifetime-disjoint)
  short* Vthi = xhi;                             // after k_gemm(qkv), x splits dead
  short* Vtlo = xlo;
  float* Wfold = (float*)Wthi;                   // after k_gemm(qkv), Wt dead (1152 B)
  short* KChi = (short*)qkvf;                    // after k_qkv_post, qkvf dead
  short* KClo = KChi + 3145728;
  float2* stats  = (float2*)((char*)qkvf + 12582912);   // 12582912 B
  float2* merged = (float2*)((char*)qkvf + 25165824);   // 393216 B (< 37748736 total)
  short* ohi = Qhi;                              // after k_scores, Q splits dead
  short* olo = Qlo;

  k_split_x<<<dim3(1536), 256, 0, stream>>>(x, xhi, xlo);
  k_split_T<<<dim3(72, 24), 256, 0, stream>>>(W_qkv, Wthi, Wtlo, 768, 2304);
  k_split_T<<<dim3(24, 24), 256, 0, stream>>>(W_proj, Wpthi, Wptlo, 768, 768);
  k_gemm<<<dim3(36, 32), 256, 0, stream>>>(xhi, xlo, Wthi, Wtlo, b_qkv, qkvf, 4096, 2304, 768);
  k_fold<<<dim3(1), 256, 0, stream>>>(W_conv, scale, riem, (float*)Wfold);
  k_qkv_post<<<dim3(32, 12, 4), 256, 0, stream>>>(qkvf, Qhi, Qlo, Khi, Klo, Vthi, Vtlo);
  k_center<<<dim3(1536), 256, 0, stream>>>(Khi, Klo, KChi, KClo);
  k_scores<<<dim3(32, 32, 4), 256, 0, stream>>>(Qhi, Qlo, Khi, Klo, KChi, KClo, (float*)Wfold, attn_out, stats);
  k_merge<<<dim3(4, 48), 256, 0, stream>>>(stats, merged);
  k_pvsm<<<dim3(32, 12, 4), 256, 0, stream>>>(attn_out, merged, Vthi, Vtlo, ohi, olo);
  k_gemm<<<dim3(12, 32), 256, 0, stream>>>(ohi, olo, Wpthi, Wptlo, b_proj, out_final, 4096, 768, 768);
}

// Round 5
// 402.264 us; speedup vs baseline: 1.3179x; 1.3179x over previous
//
#include <hip/hip_runtime.h>
#include <cstddef>
#include <cstdint>

#define B_ 4
#define N_ 1024
#define C_ 768
#define H_ 12
#define D_ 64

typedef __attribute__((ext_vector_type(8))) short bf16x8;
typedef __attribute__((ext_vector_type(4))) short s16x4;
typedef __attribute__((ext_vector_type(4))) float f32x4;

#define MFMA16(a_, b_, c_) __builtin_amdgcn_mfma_f32_16x16x32_bf16((a_), (b_), (c_), 0, 0, 0)
#define GLLDS16(gp_, lp_) __builtin_amdgcn_global_load_lds( \
    (const __attribute__((address_space(1))) unsigned int*)(gp_), \
    (__attribute__((address_space(3))) unsigned int*)(lp_), 16, 0, 0)

__device__ __forceinline__ unsigned short f2bf(float f) {
  unsigned int u = __float_as_uint(f);
  u += 0x7fffu + ((u >> 16) & 1u);
  return (unsigned short)(u >> 16);
}
__device__ __forceinline__ float bf2f(unsigned short b) {
  return __uint_as_float(((unsigned int)b) << 16);
}

// ---------------- split x (elementwise, 8 elems/thread) ----------------
__global__ __launch_bounds__(256) void k_split_x(const float* __restrict__ x,
                                                 short* __restrict__ xhi,
                                                 short* __restrict__ xlo) {
  const size_t i = ((size_t)blockIdx.x * 256 + threadIdx.x) * 8;
  float4 a = *reinterpret_cast<const float4*>(&x[i]);
  float4 b = *reinterpret_cast<const float4*>(&x[i + 4]);
  float v[8] = {a.x, a.y, a.z, a.w, b.x, b.y, b.z, b.w};
  bf16x8 hi, lo;
#pragma unroll
  for (int j = 0; j < 8; ++j) {
    unsigned short h = f2bf(v[j]);
    hi[j] = (short)h;
    lo[j] = (short)f2bf(v[j] - bf2f(h));
  }
  *reinterpret_cast<bf16x8*>(&xhi[i]) = hi;
  *reinterpret_cast<bf16x8*>(&xlo[i]) = lo;
}

// ---------------- split + transpose weights: W[Kd][Nn] -> T[Nn][Kd] hi/lo ----------------
__global__ __launch_bounds__(256) void k_split_T(const float* __restrict__ W,
                                                 short* __restrict__ Thi,
                                                 short* __restrict__ Tlo,
                                                 int Kd, int Nn) {
  __shared__ float tile[32][33];
  const int k0 = blockIdx.y * 32, n0 = blockIdx.x * 32;
  const int t = threadIdx.x;
  const int r = t >> 3, cq = (t & 7) * 4;
  float4 v = *reinterpret_cast<const float4*>(&W[(size_t)(k0 + r) * Nn + n0 + cq]);
  tile[r][cq + 0] = v.x; tile[r][cq + 1] = v.y;
  tile[r][cq + 2] = v.z; tile[r][cq + 3] = v.w;
  __syncthreads();
  const int nrow = t >> 3, kq = (t & 7) * 4;
  s16x4 hi, lo;
#pragma unroll
  for (int i = 0; i < 4; ++i) {
    float f = tile[kq + i][nrow];
    unsigned short h = f2bf(f);
    hi[i] = (short)h;
    lo[i] = (short)f2bf(f - bf2f(h));
  }
  *reinterpret_cast<s16x4*>(&Thi[(size_t)(n0 + nrow) * Kd + k0 + kq]) = hi;
  *reinterpret_cast<s16x4*>(&Tlo[(size_t)(n0 + nrow) * Kd + k0 + kq]) = lo;
}

// ---------------- fold scale/riem into W_conv ----------------
__global__ __launch_bounds__(256) void k_fold(const float* __restrict__ Wc,
                                              const float* __restrict__ scale_p,
                                              const float* __restrict__ riem_p,
                                              float* __restrict__ Wfold) {
  const int t = threadIdx.x;
  const float scale = scale_p[0], riem = riem_p[0];
  for (int i = t; i < 288; i += 256)
    Wfold[i] = Wc[i] * (((i % 24) < 12) ? scale : riem);
}

// ---------------- generic split-bf16 MFMA GEMM ----------------
// C[M][Nn] = A[M][Kd] * B^T (B stored [Nn][Kd]) + bias[n];  BM=128 BN=64 BK=32
__global__ __launch_bounds__(256) void k_gemm(const short* __restrict__ Ahi,
                                              const short* __restrict__ Alo,
                                              const short* __restrict__ Bhi,
                                              const short* __restrict__ Blo,
                                              const float* __restrict__ bias,
                                              float* __restrict__ Cout,
                                              int M, int Nn, int Kd) {
  __shared__ __align__(16) short sA[2][128 * 32];
  __shared__ __align__(16) short sB[2][64 * 32];
  const int tid = threadIdx.x;
  const int wv = tid >> 6, l = tid & 63;
  const int lr = l & 15, lg = l >> 4;
  const int row0 = blockIdx.y * 128;
  const int col0 = blockIdx.x * 64;
  const int wr = (wv >> 1) * 64;
  const int wc = (wv & 1) * 32;
  const int ar = tid >> 2, ac = tid & 3;
  f32x4 acc[4][2];
#pragma unroll
  for (int i = 0; i < 4; ++i)
#pragma unroll
    for (int j = 0; j < 2; ++j) acc[i][j] = (f32x4){0.f, 0.f, 0.f, 0.f};

  for (int k0 = 0; k0 < Kd; k0 += 32) {
#pragma unroll
    for (int j = 0; j < 2; ++j) {
      const int row = j * 64 + ar;
      const int cc = ac ^ ((row >> 1) & 3);
      const size_t so = (size_t)(row0 + row) * Kd + k0 + cc * 8;
      GLLDS16(Ahi + so, &sA[0][(j * 256 + (wv << 6)) * 8]);
      GLLDS16(Alo + so, &sA[1][(j * 256 + (wv << 6)) * 8]);
    }
    {
      const int row = ar;
      const int cc = ac ^ ((row >> 1) & 3);
      const size_t so = (size_t)(col0 + row) * Kd + k0 + cc * 8;
      GLLDS16(Bhi + so, &sB[0][(wv << 6) * 8]);
      GLLDS16(Blo + so, &sB[1][(wv << 6) * 8]);
    }
    __syncthreads();
    bf16x8 afh[4], afl[4], bfh[2], bfl[2];
#pragma unroll
    for (int ti = 0; ti < 4; ++ti) {
      const int row = wr + ti * 16 + lr;
      const int pc = lg ^ ((row >> 1) & 3);
      afh[ti] = *reinterpret_cast<const bf16x8*>(&sA[0][row * 32 + pc * 8]);
      afl[ti] = *reinterpret_cast<const bf16x8*>(&sA[1][row * 32 + pc * 8]);
    }
#pragma unroll
    for (int tj = 0; tj < 2; ++tj) {
      const int row = wc + tj * 16 + lr;
      const int pc = lg ^ ((row >> 1) & 3);
      bfh[tj] = *reinterpret_cast<const bf16x8*>(&sB[0][row * 32 + pc * 8]);
      bfl[tj] = *reinterpret_cast<const bf16x8*>(&sB[1][row * 32 + pc * 8]);
    }
#pragma unroll
    for (int ti = 0; ti < 4; ++ti)
#pragma unroll
      for (int tj = 0; tj < 2; ++tj) {
        acc[ti][tj] = MFMA16(afh[ti], bfh[tj], acc[ti][tj]);
        acc[ti][tj] = MFMA16(afl[ti], bfh[tj], acc[ti][tj]);
        acc[ti][tj] = MFMA16(afh[ti], bfl[tj], acc[ti][tj]);
      }
    __syncthreads();
  }
#pragma unroll
  for (int ti = 0; ti < 4; ++ti)
#pragma unroll
    for (int tj = 0; tj < 2; ++tj) {
      const int col = col0 + wc + tj * 16 + lr;
      const float bb = bias[col];
#pragma unroll
      for (int r = 0; r < 4; ++r) {
        const int row = row0 + wr + ti * 16 + lg * 4 + r;
        Cout[(size_t)row * Nn + col] = acc[ti][tj][r] + bb;
      }
    }
}

// ---------------- qkv post: split Q, center+split K, means, transpose+split V ----------------
__global__ __launch_bounds__(256) void k_qkv_post(const float* __restrict__ qkvf,
                                                  short* __restrict__ Qhi, short* __restrict__ Qlo,
                                                  short* __restrict__ KChi, short* __restrict__ KClo,
                                                  short* __restrict__ Vthi, short* __restrict__ Vtlo,
                                                  float* __restrict__ Qm, float* __restrict__ Km) {
  __shared__ unsigned short lvh[64][33];
  __shared__ unsigned short lvl[64][33];
  const int b = blockIdx.z, h = blockIdx.y, n0 = blockIdx.x * 32;
  const int t = threadIdx.x;
  const int row = t >> 3, d0 = (t & 7) * 8;
  const int n = n0 + row;
  const float* base = qkvf + ((size_t)(b * 1024 + n)) * 2304 + h * 64 + d0;
  const size_t qko = ((size_t)(b * H_ + h) * N_ + n) * D_ + d0;

#pragma unroll
  for (int part = 0; part < 2; ++part) {  // 0: q, 1: k (centered)
    float4 a = *reinterpret_cast<const float4*>(base + part * 768);
    float4 c = *reinterpret_cast<const float4*>(base + part * 768 + 4);
    float v[8] = {a.x, a.y, a.z, a.w, c.x, c.y, c.z, c.w};
    float s = v[0] + v[1] + v[2] + v[3] + v[4] + v[5] + v[6] + v[7];
#pragma unroll
    for (int off = 1; off < 8; off <<= 1) s += __shfl_xor(s, off);
    const float mean = s * (1.0f / 64.0f);
    if ((t & 7) == 0) (part ? Km : Qm)[(size_t)(b * H_ + h) * N_ + n] = mean;
    const float sub = part ? mean : 0.0f;
    bf16x8 hi, lo;
#pragma unroll
    for (int j = 0; j < 8; ++j) {
      const float f = v[j] - sub;
      unsigned short hh = f2bf(f);
      hi[j] = (short)hh;
      lo[j] = (short)f2bf(f - bf2f(hh));
    }
    *reinterpret_cast<bf16x8*>((part ? KChi : Qhi) + qko) = hi;
    *reinterpret_cast<bf16x8*>((part ? KClo : Qlo) + qko) = lo;
  }
  {  // v -> transposed split
    float4 a = *reinterpret_cast<const float4*>(base + 1536);
    float4 c = *reinterpret_cast<const float4*>(base + 1536 + 4);
    float v[8] = {a.x, a.y, a.z, a.w, c.x, c.y, c.z, c.w};
#pragma unroll
    for (int j = 0; j < 8; ++j) {
      unsigned short hh = f2bf(v[j]);
      lvh[d0 + j][row] = hh;
      lvl[d0 + j][row] = f2bf(v[j] - bf2f(hh));
    }
  }
  __syncthreads();
  const int d = t >> 2, c = t & 3;
  bf16x8 vh, vl;
#pragma unroll
  for (int i = 0; i < 8; ++i) {
    vh[i] = (short)lvh[d][c * 8 + i];
    vl[i] = (short)lvl[d][c * 8 + i];
  }
  const size_t vo = ((size_t)(b * H_ + h) * D_ + d) * N_ + n0 + c * 8;
  *reinterpret_cast<bf16x8*>(Vthi + vo) = vh;
  *reinterpret_cast<bf16x8*>(Vtlo + vo) = vl;
}

// ---------------- scores + channel mix -> logits (+ partial softmax stats) ----------------
// u = q.kc (MFMA, kc centered); s = u + 64*qm*km; logit[o] = sum_h We'[o,h]*s + Wr'[o,h]*u^2
__global__ __launch_bounds__(256, 3) void k_scores(
    const short* __restrict__ Qhi, const short* __restrict__ Qlo,
    const short* __restrict__ KChi, const short* __restrict__ KClo,
    const float* __restrict__ Qm, const float* __restrict__ Km,
    const float* __restrict__ Wfold, float* __restrict__ logits,
    float2* __restrict__ stats) {
  __shared__ __align__(16) short sQh[2][32 * 64];
  __shared__ __align__(16) short sQl[2][32 * 64];
  __shared__ __align__(16) short sCh[2][32 * 64];
  __shared__ __align__(16) short sCl[2][32 * 64];
  __shared__ float sQm[12][32];
  __shared__ float sKm[12][32];
  __shared__ float sWf[288];
  __shared__ float2 sbuf[4][12][16];

  const int t = threadIdx.x;
  const int b = blockIdx.z;
  const int n0 = blockIdx.y * 32, m0 = blockIdx.x * 32;
  const int wv = t >> 6, l = t & 63;
  const int lr = l & 15, lg = l >> 4;
  const size_t bh0 = (size_t)b * H_;

  for (int i = t; i < 384; i += 256)
    sQm[i >> 5][i & 31] = Qm[(bh0 + (i >> 5)) * N_ + n0 + (i & 31)];
  for (int i = t; i < 384; i += 256)
    sKm[i >> 5][i & 31] = Km[(bh0 + (i >> 5)) * N_ + m0 + (i & 31)];
  for (int i = t; i < 288; i += 256) sWf[i] = Wfold[i];

  const int srow = t >> 3;                  // 0..31
  const int scs = (t & 7) ^ (srow & 7);     // XOR-swizzled source chunk
  const size_t qsrc = (bh0 * N_ + n0 + srow) * D_ + scs * 8;
  const size_t csrc = (bh0 * N_ + m0 + srow) * D_ + scs * 8;
  const size_t hstep = (size_t)N_ * D_;

  GLLDS16(Qhi + qsrc, &sQh[0][wv * 512]);
  GLLDS16(Qlo + qsrc, &sQl[0][wv * 512]);
  GLLDS16(KChi + csrc, &sCh[0][wv * 512]);
  GLLDS16(KClo + csrc, &sCl[0][wv * 512]);
  __syncthreads();

  f32x4 acc[12];
#pragma unroll
  for (int o = 0; o < 12; ++o) acc[o] = (f32x4){0.f, 0.f, 0.f, 0.f};

  const int arow = (wv >> 1) * 16 + lr;
  const int brow = (wv & 1) * 16 + lr;
  const int ai0 = arow * 64 + ((lg + 0) ^ (arow & 7)) * 8;
  const int ai1 = arow * 64 + ((lg + 4) ^ (arow & 7)) * 8;
  const int bi0 = brow * 64 + ((lg + 0) ^ (brow & 7)) * 8;
  const int bi1 = brow * 64 + ((lg + 4) ^ (brow & 7)) * 8;

  int buf = 0;
  for (int h = 0; h < H_; ++h) {
    if (h < 11) {
      const size_t qs = qsrc + (size_t)(h + 1) * hstep;
      const size_t cs = csrc + (size_t)(h + 1) * hstep;
      GLLDS16(Qhi + qs, &sQh[buf ^ 1][wv * 512]);
      GLLDS16(Qlo + qs, &sQl[buf ^ 1][wv * 512]);
      GLLDS16(KChi + cs, &sCh[buf ^ 1][wv * 512]);
      GLLDS16(KClo + cs, &sCl[buf ^ 1][wv * 512]);
    }
    const bf16x8 qh0 = *reinterpret_cast<const bf16x8*>(&sQh[buf][ai0]);
    const bf16x8 qh1 = *reinterpret_cast<const bf16x8*>(&sQh[buf][ai1]);
    const bf16x8 ql0 = *reinterpret_cast<const bf16x8*>(&sQl[buf][ai0]);
    const bf16x8 ql1 = *reinterpret_cast<const bf16x8*>(&sQl[buf][ai1]);
    const bf16x8 ch0 = *reinterpret_cast<const bf16x8*>(&sCh[buf][bi0]);
    const bf16x8 ch1 = *reinterpret_cast<const bf16x8*>(&sCh[buf][bi1]);
    const bf16x8 cl0 = *reinterpret_cast<const bf16x8*>(&sCl[buf][bi0]);
    const bf16x8 cl1 = *reinterpret_cast<const bf16x8*>(&sCl[buf][bi1]);

    f32x4 ua = {0.f, 0.f, 0.f, 0.f}, ub = {0.f, 0.f, 0.f, 0.f};
    ua = MFMA16(qh0, ch0, ua);  ub = MFMA16(qh1, ch1, ub);
    ua = MFMA16(qh0, cl0, ua);  ub = MFMA16(qh1, cl1, ub);
    ua = MFMA16(ql0, ch0, ua);  ub = MFMA16(ql1, ch1, ub);

    const float4 qm4 = *reinterpret_cast<const float4*>(&sQm[h][(wv >> 1) * 16 + lg * 4]);
    const float km64 = 64.0f * sKm[h][(wv & 1) * 16 + lr];
    const float qmv[4] = {qm4.x, qm4.y, qm4.z, qm4.w};
    float sv[4], u2[4];
#pragma unroll
    for (int r = 0; r < 4; ++r) {
      const float u = ua[r] + ub[r];
      sv[r] = fmaf(km64, qmv[r], u);
      u2[r] = u * u;
    }
#pragma unroll
    for (int o = 0; o < 12; ++o) {
      const float we = sWf[o * 24 + h];
      const float wr = sWf[o * 24 + 12 + h];
#pragma unroll
      for (int r = 0; r < 4; ++r)
        acc[o][r] = fmaf(we, sv[r], fmaf(wr, u2[r], acc[o][r]));
    }
    __syncthreads();
    buf ^= 1;
  }

#pragma unroll
  for (int o = 0; o < 12; ++o) {
    float* dst = &logits[((bh0 + o) * N_ + n0 + (wv >> 1) * 16) * N_ + m0 + (wv & 1) * 16 + lr];
#pragma unroll
    for (int r = 0; r < 4; ++r)
      dst[(size_t)(lg * 4 + r) * N_] = acc[o][r];
  }
#pragma unroll
  for (int o = 0; o < 12; ++o) {
    float mx4[4], ss4[4];
#pragma unroll
    for (int r = 0; r < 4; ++r) {
      float mx = acc[o][r];
      mx = fmaxf(mx, __shfl_xor(mx, 1));
      mx = fmaxf(mx, __shfl_xor(mx, 2));
      mx = fmaxf(mx, __shfl_xor(mx, 4));
      mx = fmaxf(mx, __shfl_xor(mx, 8));
      float e = __expf(acc[o][r] - mx);
      e += __shfl_xor(e, 1);
      e += __shfl_xor(e, 2);
      e += __shfl_xor(e, 4);
      e += __shfl_xor(e, 8);
      mx4[r] = mx; ss4[r] = e;
    }
    if (lr < 4) sbuf[wv][o][lg * 4 + lr] = make_float2(mx4[lr], ss4[lr]);
  }
  __syncthreads();
  if ((wv & 1) == 0) {
    for (int i = l; i < 192; i += 64) {
      const int o = i >> 4, row = i & 15;
      const float2 p0 = sbuf[wv][o][row];
      const float2 p1 = sbuf[wv + 1][o][row];
      const float M = fmaxf(p0.x, p1.x);
      const float S = p0.y * __expf(p0.x - M) + p1.y * __expf(p1.x - M);
      const int n = n0 + (wv >> 1) * 16 + row;
      stats[(((size_t)b * 12 + o) * 32 + blockIdx.x) * 1024 + n] = make_float2(M, S);
    }
  }
}

// ---------------- merge partial stats -> per-row (M, 1/S) ----------------
__global__ __launch_bounds__(256) void k_merge(const float2* __restrict__ stats,
                                               float2* __restrict__ merged) {
  const int bo = blockIdx.y;
  const int n = blockIdx.x * 256 + threadIdx.x;
  float M = -3.0e38f, S = 0.f;
  for (int seg = 0; seg < 32; ++seg) {
    const float2 p = stats[((size_t)bo * 32 + seg) * 1024 + n];
    if (p.x > M) {
      S = S * __expf(M - p.x) + p.y;
      M = p.x;
    } else {
      S += p.y * __expf(p.x - M);
    }
  }
  merged[(size_t)bo * 1024 + n] = make_float2(M, 1.0f / S);
}

// ---------------- fused softmax + attn-write + PV MFMA + split epilogue ----------------
__global__ __launch_bounds__(256) void k_pvsm(float* __restrict__ attn,
                                              const float2* __restrict__ merged,
                                              const short* __restrict__ Vthi,
                                              const short* __restrict__ Vtlo,
                                              short* __restrict__ ohi,
                                              short* __restrict__ olo) {
  __shared__ __align__(16) short sPhi[32 * 32];
  __shared__ __align__(16) short sPlo[32 * 32];
  __shared__ __align__(16) short sVhi[64 * 32];
  __shared__ __align__(16) short sVlo[64 * 32];
  __shared__ float sM[32], sIS[32];
  const int b = blockIdx.z, o = blockIdx.y;
  const int n0 = blockIdx.x * 32;
  const int bo = b * H_ + o;
  const int t = threadIdx.x;
  const int wv = t >> 6, l = t & 63;
  const int lr = l & 15, lg = l >> 4;
  const int nsub = (wv & 1) * 16, dsub = (wv >> 1) * 32;

  if (t < 32) {
    const float2 ms = merged[(size_t)bo * 1024 + n0 + t];
    sM[t] = ms.x;
    sIS[t] = ms.y;
  }
  __syncthreads();

  const int prow = t >> 3, pc4 = (t & 7) * 4;
  float* lrow = attn + ((size_t)bo * N_ + n0 + prow) * N_ + pc4;
  const int vd = t >> 2, vc = t & 3;
  const int vcc = vc ^ ((vd >> 1) & 3);
  const size_t vsrc0 = ((size_t)bo * D_ + vd) * N_ + vcc * 8;
  const int pchunk = (pc4 >> 3) ^ ((prow >> 1) & 3);
  const int pofs = prow * 32 + pchunk * 8 + (t & 1) * 4;

  f32x4 acc[2];
  acc[0] = (f32x4){0.f, 0.f, 0.f, 0.f};
  acc[1] = (f32x4){0.f, 0.f, 0.f, 0.f};

  for (int ms = 0; ms < 32; ++ms) {
    const int m0 = ms * 32;
    GLLDS16(Vthi + vsrc0 + m0, &sVhi[(wv << 6) * 8]);
    GLLDS16(Vtlo + vsrc0 + m0, &sVlo[(wv << 6) * 8]);
    float4 lv = *reinterpret_cast<const float4*>(&lrow[m0]);
    const float Mr = sM[prow], iS = sIS[prow];
    float4 p;
    p.x = __expf(lv.x - Mr) * iS;
    p.y = __expf(lv.y - Mr) * iS;
    p.z = __expf(lv.z - Mr) * iS;
    p.w = __expf(lv.w - Mr) * iS;
    *reinterpret_cast<float4*>(&lrow[m0]) = p;
    const float pv[4] = {p.x, p.y, p.z, p.w};
    s16x4 phi, plo;
#pragma unroll
    for (int j = 0; j < 4; ++j) {
      unsigned short hh = f2bf(pv[j]);
      phi[j] = (short)hh;
      plo[j] = (short)f2bf(pv[j] - bf2f(hh));
    }
    *reinterpret_cast<s16x4*>(&sPhi[pofs]) = phi;
    *reinterpret_cast<s16x4*>(&sPlo[pofs]) = plo;
    __syncthreads();
    const int arow = nsub + lr;
    const int apc = lg ^ ((arow >> 1) & 3);
    const bf16x8 pa = *reinterpret_cast<const bf16x8*>(&sPhi[arow * 32 + apc * 8]);
    const bf16x8 pb = *reinterpret_cast<const bf16x8*>(&sPlo[arow * 32 + apc * 8]);
#pragma unroll
    for (int dt = 0; dt < 2; ++dt) {
      const int drow = dsub + dt * 16 + lr;
      const int dpc = lg ^ ((drow >> 1) & 3);
      const bf16x8 vh = *reinterpret_cast<const bf16x8*>(&sVhi[drow * 32 + dpc * 8]);
      const bf16x8 vl = *reinterpret_cast<const bf16x8*>(&sVlo[drow * 32 + dpc * 8]);
      acc[dt] = MFMA16(pa, vh, acc[dt]);
      acc[dt] = MFMA16(pb, vh, acc[dt]);
      acc[dt] = MFMA16(pa, vl, acc[dt]);
    }
    __syncthreads();
  }
#pragma unroll
  for (int dt = 0; dt < 2; ++dt) {
    const int d = dsub + dt * 16 + lr;
#pragma unroll
    for (int r = 0; r < 4; ++r) {
      const int n = n0 + nsub + lg * 4 + r;
      const float val = acc[dt][r];
      const unsigned short hh = f2bf(val);
      const size_t oo = (size_t)(b * 1024 + n) * 768 + o * 64 + d;
      ohi[oo] = (short)hh;
      olo[oo] = (short)f2bf(val - bf2f(hh));
    }
  }
}

extern "C" void kernel_launch(void* const* d_in, const int* in_sizes, int n_in,
                              void* d_out, int out_size, void* d_ws, size_t ws_size,
                              hipStream_t stream) {
  (void)in_sizes; (void)n_in; (void)out_size; (void)ws_size;
  const float* x      = (const float*)d_in[0];
  const float* W_qkv  = (const float*)d_in[1];
  const float* b_qkv  = (const float*)d_in[2];
  const float* scale  = (const float*)d_in[3];
  const float* riem   = (const float*)d_in[4];
  const float* W_conv = (const float*)d_in[5];
  // d_in[6] = b_conv: constant along softmax axis -> softmax-invariant, skipped
  const float* W_proj = (const float*)d_in[7];
  const float* b_proj = (const float*)d_in[8];

  float* out_final = (float*)d_out;                     // [B,N,C]
  float* attn_out  = out_final + (size_t)B_ * N_ * C_;  // [B,H,N,N] logits -> attn in-place

  char* w = (char*)d_ws;
  short* xhi  = (short*)w;                       // 6291456 B
  short* xlo  = xhi + 3145728;                   // 6291456 B
  short* Wthi = (short*)(w + 12582912);          // 3538944 B
  short* Wtlo = Wthi + 1769472;                  // 3538944 B
  short* Wpthi = (short*)(w + 19660800);         // 1179648 B
  short* Wptlo = Wpthi + 589824;                 // 1179648 B
  float* qkvf = (float*)(w + 22020096);          // 37748736 B
  short* Qhi  = (short*)(w + 59768832);
  short* Qlo  = Qhi + 3145728;
  short* KChi = Qlo + 3145728;
  short* KClo = KChi + 3145728;                  // ws end: 84934656 B
  // aliases (lifetime-disjoint)
  short* Vthi = xhi;                             // after k_gemm(qkv), x splits dead
  short* Vtlo = xlo;
  float* Wfold = (float*)Wthi;                   // Wt dead after qkv gemm (1152 B)
  float* Qm = (float*)((char*)Wthi + 8192);      // 196608 B
  float* Km = (float*)((char*)Wthi + 8192 + 196608);
  float2* stats  = (float2*)((char*)qkvf + 12582912);
  float2* merged = (float2*)((char*)qkvf + 25165824);
  short* ohi = Qhi;                              // after k_scores, Q splits dead
  short* olo = Qlo;

  k_split_x<<<dim3(1536), 256, 0, stream>>>(x, xhi, xlo);
  k_split_T<<<dim3(72, 24), 256, 0, stream>>>(W_qkv, Wthi, Wtlo, 768, 2304);
  k_split_T<<<dim3(24, 24), 256, 0, stream>>>(W_proj, Wpthi, Wptlo, 768, 768);
  k_gemm<<<dim3(36, 32), 256, 0, stream>>>(xhi, xlo, Wthi, Wtlo, b_qkv, qkvf, 4096, 2304, 768);
  k_fold<<<dim3(1), 256, 0, stream>>>(W_conv, scale, riem, Wfold);
  k_qkv_post<<<dim3(32, 12, 4), 256, 0, stream>>>(qkvf, Qhi, Qlo, KChi, KClo, Vthi, Vtlo, Qm, Km);
  k_scores<<<dim3(32, 32, 4), 256, 0, stream>>>(Qhi, Qlo, KChi, KClo, Qm, Km, Wfold, attn_out, stats);
  k_merge<<<dim3(4, 48), 256, 0, stream>>>(stats, merged);
  k_pvsm<<<dim3(32, 12, 4), 256, 0, stream>>>(attn_out, merged, Vthi, Vtlo, ohi, olo);
  k_gemm<<<dim3(12, 32), 256, 0, stream>>>(ohi, olo, Wpthi, Wptlo, b_proj, out_final, 4096, 768, 768);
}